// Round 2
// baseline (89.752 us; speedup 1.0000x reference)
//
#include <hip/hip_runtime.h>

// DPConv (KERNEL=8, EXT=4, STRIDE=4) on (8,64,128,128) f32.
// K=16,k=8 -> adaptive bins degenerate to exact 2x2 pools; op is separable.
// Vertical pass (global->LDS), per output row h, m=h&3:
//   U[h] = ( [h<124]*(x[max(h+m-4,0)] + x[max(h+m-3,0)])
//          + [h>=4 ]*(x[min(h+m,127)] + x[min(h+m+1,127)]) ) / (2*cnt)
// Horizontal pass (LDS->global) is identical along W. Verified by hand at
// h=0 (2*x0/2), h=127 (rows 130,131 -> 127,127), and interior.
// Along W, for an aligned group w=4t..4t+3: f1=(t<=30), f2=(t>=1) are
// UNIFORM over the group, and all 12 needed columns live in the three
// float4 windows L=[4t-4..4t-1], M=[4t..4t+3], R=[4t+4..4t+7]
// (edges: L->broadcast(M.x) at t=0, R->broadcast(M.w) at t=31).

#define HH 128
#define WW 128

__global__ __launch_bounds__(256) void dpconv_kernel(const float* __restrict__ x,
                                                     float* __restrict__ out) {
    __shared__ float U[HH][WW];   // 64 KB -> 2 blocks/CU, 16 waves/CU

    const int plane = blockIdx.x;
    const float* __restrict__ xp = x + (size_t)plane * (HH * WW);
    float* __restrict__ op       = out + (size_t)plane * (HH * WW);

    // ---- Pass 1: vertical 4-tap (global -> LDS), float4 over columns ----
    #pragma unroll 4
    for (int it = 0; it < (HH * (WW / 4)) / 256; ++it) {
        const int e = it * 256 + threadIdx.x;
        const int h = e >> 5;            // 32 float4-items per row
        const int c = (e & 31) << 2;
        const int m = h & 3;
        const bool t1 = (h < 124);
        const bool t2 = (h >= 4);
        const int ra0 = max(h + m - 4, 0);
        const int ra1 = max(h + m - 3, 0);
        const int rb0 = min(h + m,     127);
        const int rb1 = min(h + m + 1, 127);

        const float4 a0 = *reinterpret_cast<const float4*>(xp + ra0 * WW + c);
        const float4 a1 = *reinterpret_cast<const float4*>(xp + ra1 * WW + c);
        const float4 b0 = *reinterpret_cast<const float4*>(xp + rb0 * WW + c);
        const float4 b1 = *reinterpret_cast<const float4*>(xp + rb1 * WW + c);

        const float f1 = t1 ? 1.0f : 0.0f;
        const float f2 = t2 ? 1.0f : 0.0f;
        const float sc = (t1 && t2) ? 0.25f : 0.5f;

        float4 r;
        r.x = (f1 * (a0.x + a1.x) + f2 * (b0.x + b1.x)) * sc;
        r.y = (f1 * (a0.y + a1.y) + f2 * (b0.y + b1.y)) * sc;
        r.z = (f1 * (a0.z + a1.z) + f2 * (b0.z + b1.z)) * sc;
        r.w = (f1 * (a0.w + a1.w) + f2 * (b0.w + b1.w)) * sc;
        *reinterpret_cast<float4*>(&U[h][c]) = r;
    }

    __syncthreads();

    // ---- Pass 2: horizontal 4-tap (LDS -> global), 4 outputs/item ----
    #pragma unroll 4
    for (int it = 0; it < (HH * (WW / 4)) / 256; ++it) {
        const int e  = it * 256 + threadIdx.x;
        const int hr = e >> 5;
        const int t  = e & 31;           // output cols 4t..4t+3

        const float4 M  = *reinterpret_cast<const float4*>(&U[hr][t << 2]);
        const float4 Lr = *reinterpret_cast<const float4*>(&U[hr][max((t << 2) - 4, 0)]);
        const float4 Rr = *reinterpret_cast<const float4*>(&U[hr][min((t << 2) + 4, 124)]);

        const float4 L = (t > 0)  ? Lr : make_float4(M.x, M.x, M.x, M.x);
        const float4 R = (t < 31) ? Rr : make_float4(M.w, M.w, M.w, M.w);

        const float f1 = (t < 31) ? 1.0f : 0.0f;   // w<124 uniform over group
        const float f2 = (t > 0)  ? 1.0f : 0.0f;   // w>=4  uniform over group
        const float sc = (t == 0 || t == 31) ? 0.5f : 0.25f;

        // lm = cols 4t-4..4t+3 (clamped), mr = cols 4t..4t+7 (clamped)
        const float lm0 = L.x, lm1 = L.y, lm2 = L.z, lm3 = L.w;
        const float lm4 = M.x, lm5 = M.y, lm6 = M.z, lm7 = M.w;
        const float mr0 = M.x, mr1 = M.y, mr2 = M.z, mr3 = M.w;
        const float mr4 = R.x, mr5 = R.y, mr6 = R.z, mr7 = R.w;

        float4 o;
        o.x = (f1 * (lm0 + lm1) + f2 * (mr0 + mr1)) * sc;  // w = 4t+0
        o.y = (f1 * (lm2 + lm3) + f2 * (mr2 + mr3)) * sc;  // w = 4t+1
        o.z = (f1 * (lm4 + lm5) + f2 * (mr4 + mr5)) * sc;  // w = 4t+2
        o.w = (f1 * (lm6 + lm7) + f2 * (mr6 + mr7)) * sc;  // w = 4t+3
        *reinterpret_cast<float4*>(op + hr * WW + (t << 2)) = o;
    }
}

extern "C" void kernel_launch(void* const* d_in, const int* in_sizes, int n_in,
                              void* d_out, int out_size, void* d_ws, size_t ws_size,
                              hipStream_t stream) {
    const float* x = (const float*)d_in[0];
    float* out     = (float*)d_out;
    const int planes = in_sizes[0] / (HH * WW);   // 8*64 = 512
    dpconv_kernel<<<planes, 256, 0, stream>>>(x, out);
}

// Round 3
// 80.070 us; speedup vs baseline: 1.1209x; 1.1209x over previous
//
#include <hip/hip_runtime.h>

// DPConv (KERNEL=8, EXT=4, STRIDE=4) on (8,64,128,128) f32.
// K=16,k=8 -> adaptive bins degenerate to exact 2x2 pools; op is separable.
// Vertical pass (global->LDS), per output row h, m=h&3:
//   U[h] = ( [h<124]*(x[max(h+m-4,0)] + x[max(h+m-3,0)])
//          + [h>=4 ]*(x[min(h+m,127)] + x[min(h+m+1,127)]) ) / (2*cnt)
// Horizontal pass (LDS->global) is identical along W.
// R2 experiment: RCH 128 -> 32 (LDS 64KB -> 16KB): occupancy 2 -> 8
// blocks/CU (8 -> 32 waves/CU) to hide HBM + barrier latency. Halo rows
// (h0-4 .. h0+36) re-read across chunks are L2/L3 hits; HBM traffic
// unchanged (input read-once, output write-once).

#define HH 128
#define WW 128
#define RCH 32    // rows per block; LDS = 32*128*4 = 16 KB

__global__ __launch_bounds__(256) void dpconv_kernel(const float* __restrict__ x,
                                                     float* __restrict__ out) {
    __shared__ float U[RCH][WW];

    const int bid   = blockIdx.x;
    const int plane = bid >> 2;              // HH/RCH == 4 chunks per plane
    const int h0    = (bid & 3) * RCH;

    const float* __restrict__ xp = x + (size_t)plane * (HH * WW);
    float* __restrict__ op       = out + (size_t)plane * (HH * WW) + (size_t)h0 * WW;

    // ---- Pass 1: vertical 4-tap (global -> LDS), float4 over columns ----
    #pragma unroll
    for (int it = 0; it < (RCH * (WW / 4)) / 256; ++it) {
        const int e  = it * 256 + threadIdx.x;
        const int hr = e >> 5;               // 32 float4-items per row
        const int c  = (e & 31) << 2;
        const int h  = h0 + hr;
        const int m  = h & 3;
        const bool t1 = (h < 124);
        const bool t2 = (h >= 4);
        const int ra0 = max(h + m - 4, 0);
        const int ra1 = max(h + m - 3, 0);
        const int rb0 = min(h + m,     127);
        const int rb1 = min(h + m + 1, 127);

        const float4 a0 = *reinterpret_cast<const float4*>(xp + ra0 * WW + c);
        const float4 a1 = *reinterpret_cast<const float4*>(xp + ra1 * WW + c);
        const float4 b0 = *reinterpret_cast<const float4*>(xp + rb0 * WW + c);
        const float4 b1 = *reinterpret_cast<const float4*>(xp + rb1 * WW + c);

        const float f1 = t1 ? 1.0f : 0.0f;
        const float f2 = t2 ? 1.0f : 0.0f;
        const float sc = (t1 && t2) ? 0.25f : 0.5f;

        float4 r;
        r.x = (f1 * (a0.x + a1.x) + f2 * (b0.x + b1.x)) * sc;
        r.y = (f1 * (a0.y + a1.y) + f2 * (b0.y + b1.y)) * sc;
        r.z = (f1 * (a0.z + a1.z) + f2 * (b0.z + b1.z)) * sc;
        r.w = (f1 * (a0.w + a1.w) + f2 * (b0.w + b1.w)) * sc;
        *reinterpret_cast<float4*>(&U[hr][c]) = r;
    }

    __syncthreads();

    // ---- Pass 2: horizontal 4-tap (LDS -> global), 4 outputs/item ----
    // Group w=4t..4t+3: f1=(t<=30), f2=(t>=1) uniform over the group; all 12
    // needed columns live in windows L=[4t-4..], M=[4t..], R=[4t+4..]
    // (edges: L->broadcast(M.x) at t=0, R->broadcast(M.w) at t=31).
    #pragma unroll
    for (int it = 0; it < (RCH * (WW / 4)) / 256; ++it) {
        const int e  = it * 256 + threadIdx.x;
        const int hr = e >> 5;
        const int t  = e & 31;               // output cols 4t..4t+3

        const float4 M  = *reinterpret_cast<const float4*>(&U[hr][t << 2]);
        const float4 Lr = *reinterpret_cast<const float4*>(&U[hr][max((t << 2) - 4, 0)]);
        const float4 Rr = *reinterpret_cast<const float4*>(&U[hr][min((t << 2) + 4, 124)]);

        const float4 L = (t > 0)  ? Lr : make_float4(M.x, M.x, M.x, M.x);
        const float4 R = (t < 31) ? Rr : make_float4(M.w, M.w, M.w, M.w);

        const float f1 = (t < 31) ? 1.0f : 0.0f;
        const float f2 = (t > 0)  ? 1.0f : 0.0f;
        const float sc = (t == 0 || t == 31) ? 0.5f : 0.25f;

        float4 o;
        o.x = (f1 * (L.x + L.y) + f2 * (M.x + M.y)) * sc;  // w = 4t+0
        o.y = (f1 * (L.z + L.w) + f2 * (M.z + M.w)) * sc;  // w = 4t+1
        o.z = (f1 * (M.x + M.y) + f2 * (R.x + R.y)) * sc;  // w = 4t+2
        o.w = (f1 * (M.z + M.w) + f2 * (R.z + R.w)) * sc;  // w = 4t+3
        *reinterpret_cast<float4*>(op + hr * WW + (t << 2)) = o;
    }
}

extern "C" void kernel_launch(void* const* d_in, const int* in_sizes, int n_in,
                              void* d_out, int out_size, void* d_ws, size_t ws_size,
                              hipStream_t stream) {
    const float* x = (const float*)d_in[0];
    float* out     = (float*)d_out;
    const int planes = in_sizes[0] / (HH * WW);   // 8*64 = 512
    dpconv_kernel<<<planes * (HH / RCH), 256, 0, stream>>>(x, out);
}